// Round 1
// baseline (1546.890 us; speedup 1.0000x reference)
//
#include <hip/hip_runtime.h>

#define NUM_USER 60000
#define NUM_ITEM 40000
#define NN 100000
#define NE 500000
#define DIM 64
#define KF 4

// sum within each 16-lane group of the wave
__device__ __forceinline__ float red16(float v) {
    v += __shfl_xor(v, 1);
    v += __shfl_xor(v, 2);
    v += __shfl_xor(v, 4);
    v += __shfl_xor(v, 8);
    return v;
}

__global__ void k_init(const float* __restrict__ user, const float* __restrict__ item,
                       float* __restrict__ ego, float* __restrict__ allemb) {
    int i = blockIdx.x * blockDim.x + threadIdx.x;
    if (i >= NN * DIM) return;
    float v = (i < NUM_USER * DIM) ? user[i] : item[i - NUM_USER * DIM];
    ego[i] = v;
    allemb[i] = v;
}

__global__ void k_deg(const int* __restrict__ row0, const int* __restrict__ col0,
                      float* __restrict__ deg) {
    int e = blockIdx.x * blockDim.x + threadIdx.x;
    if (e >= NE) return;
    atomicAdd(&deg[row0[e]], 1.0f);
    atomicAdd(&deg[col0[e]], 1.0f);
}

__global__ void k_dinv(float* __restrict__ deg) {
    int i = blockIdx.x * blockDim.x + threadIdx.x;
    if (i >= NN) return;
    float d = deg[i];
    deg[i] = (d > 0.0f) ? (1.0f / sqrtf(d)) : 0.0f;
}

__global__ void k_norm(const int* __restrict__ row0, const int* __restrict__ col0,
                       const float* __restrict__ dinv, float* __restrict__ norm) {
    int e = blockIdx.x * blockDim.x + threadIdx.x;
    if (e >= NE) return;
    norm[e] = dinv[row0[e]] * dinv[col0[e]];
}

__global__ void k_softmax(const float* __restrict__ Sin, float* __restrict__ softS) {
    int e = blockIdx.x * blockDim.x + threadIdx.x;
    if (e >= NE) return;
    float s0 = Sin[e], s1 = Sin[NE + e], s2 = Sin[2 * NE + e], s3 = Sin[3 * NE + e];
    float m = fmaxf(fmaxf(s0, s1), fmaxf(s2, s3));
    float e0 = expf(s0 - m), e1 = expf(s1 - m), e2 = expf(s2 - m), e3 = expf(s3 - m);
    float inv = 1.0f / (e0 + e1 + e2 + e3);
    softS[e] = e0 * inv;
    softS[NE + e] = e1 * inv;
    softS[2 * NE + e] = e2 * inv;
    softS[3 * NE + e] = e3 * inv;
}

// one wave per directed edge: xnew[dst] += norm*softS[k] * ego[src]
__global__ void k_conv(const int* __restrict__ row0, const int* __restrict__ col0,
                       const float* __restrict__ norm, const float* __restrict__ softS,
                       const float* __restrict__ ego, float* __restrict__ xnew) {
    int wid = (blockIdx.x * blockDim.x + threadIdx.x) >> 6;
    int lane = threadIdx.x & 63;
    if (wid >= 2 * NE) return;
    int dir = (wid >= NE) ? 1 : 0;
    int e = wid - dir * NE;
    int a = row0[e], b = col0[e];
    int src = dir ? b : a;
    int dst = dir ? a : b;
    int k = lane >> 4;
    float w = norm[e] * softS[k * NE + e];
    atomicAdd(&xnew[dst * DIM + lane], w * ego[src * DIM + lane]);
}

// one wave per (original) edge: S_out[k][e] = softS[k][e] + dot(l2n(xnew[row]), tanh(l2n(ego[col])))
__global__ void k_score(const int* __restrict__ row0, const int* __restrict__ col0,
                        const float* __restrict__ softS, const float* __restrict__ xnew,
                        const float* __restrict__ ego, float* __restrict__ Sout) {
    int wid = (blockIdx.x * blockDim.x + threadIdx.x) >> 6;
    int lane = threadIdx.x & 63;
    if (wid >= NE) return;
    int r = row0[wid], c = col0[wid];
    float xu = xnew[r * DIM + lane];
    float xv = ego[c * DIM + lane];
    float ssu = red16(xu * xu);
    float ssv = red16(xv * xv);
    float u = xu / fmaxf(sqrtf(ssu), 1e-12f);
    float v = xv / fmaxf(sqrtf(ssv), 1e-12f);
    float p = red16(u * tanhf(v));
    if ((lane & 15) == 0) {
        int k = lane >> 4;
        Sout[k * NE + wid] = softS[k * NE + wid] + p;
    }
}

__global__ void k_accum(const float* __restrict__ xnew, float* __restrict__ allemb) {
    int i = blockIdx.x * blockDim.x + threadIdx.x;
    if (i >= NN * DIM) return;
    allemb[i] += xnew[i];
}

extern "C" void kernel_launch(void* const* d_in, const int* in_sizes, int n_in,
                              void* d_out, int out_size, void* d_ws, size_t ws_size,
                              hipStream_t stream) {
    const float* user = (const float*)d_in[0];
    const float* item = (const float*)d_in[1];
    const float* S_in = (const float*)d_in[2];
    const int* edge = (const int*)d_in[3];
    const int* row0 = edge;
    const int* col0 = edge + NE;

    float* out = (float*)d_out;
    float* allemb = out;              // NN*DIM floats
    float* Scur = out + NN * DIM;     // KF*NE floats (final S lives here)

    float* ws = (float*)d_ws;
    float* deg = ws;                  // NN
    float* norm = ws + NN;            // NE
    float* egoA = ws + NN + NE;       // NN*DIM
    float* egoB = egoA + NN * DIM;    // NN*DIM
    float* softS = egoB + NN * DIM;   // KF*NE

    hipMemsetAsync(deg, 0, NN * sizeof(float), stream);
    hipMemcpyAsync(Scur, S_in, (size_t)KF * NE * sizeof(float),
                   hipMemcpyDeviceToDevice, stream);

    k_init<<<(NN * DIM + 255) / 256, 256, 0, stream>>>(user, item, egoA, allemb);
    k_deg<<<(NE + 255) / 256, 256, 0, stream>>>(row0, col0, deg);
    k_dinv<<<(NN + 255) / 256, 256, 0, stream>>>(deg);
    k_norm<<<(NE + 255) / 256, 256, 0, stream>>>(row0, col0, deg, norm);

    float* ego = egoA;
    float* xnew = egoB;
    for (int layer = 0; layer < 2; ++layer) {
        for (int it = 0; it < 2; ++it) {
            k_softmax<<<(NE + 255) / 256, 256, 0, stream>>>(Scur, softS);
            hipMemsetAsync(xnew, 0, (size_t)NN * DIM * sizeof(float), stream);
            k_conv<<<(2 * NE * 64) / 256, 256, 0, stream>>>(row0, col0, norm, softS, ego, xnew);
            k_score<<<(NE * 64) / 256, 256, 0, stream>>>(row0, col0, softS, xnew, ego, Scur);
        }
        k_accum<<<(NN * DIM + 255) / 256, 256, 0, stream>>>(xnew, allemb);
        float* t = ego; ego = xnew; xnew = t;
    }
}

// Round 2
// 1329.754 us; speedup vs baseline: 1.1633x; 1.1633x over previous
//
#include <hip/hip_runtime.h>

#define NUM_USER 60000
#define NUM_ITEM 40000
#define NN 100000
#define NE 500000
#define DIM 64
#define KF 4
#define SCAN_CHUNK 512
#define NBLK_SCAN ((NN + SCAN_CHUNK - 1) / SCAN_CHUNK)   // 196

// sum within each 16-lane group of the wave
__device__ __forceinline__ float red16(float v) {
    v += __shfl_xor(v, 1);
    v += __shfl_xor(v, 2);
    v += __shfl_xor(v, 4);
    v += __shfl_xor(v, 8);
    return v;
}

__global__ void k_init(const float* __restrict__ user, const float* __restrict__ item,
                       float* __restrict__ ego, float* __restrict__ allemb) {
    int i = blockIdx.x * blockDim.x + threadIdx.x;
    if (i >= NN * DIM) return;
    float v = (i < NUM_USER * DIM) ? user[i] : item[i - NUM_USER * DIM];
    ego[i] = v;
    allemb[i] = v;
}

__global__ void k_count(const int* __restrict__ row0, const int* __restrict__ col0,
                        int* __restrict__ cnt) {
    int e = blockIdx.x * blockDim.x + threadIdx.x;
    if (e >= NE) return;
    atomicAdd(&cnt[row0[e]], 1);
    atomicAdd(&cnt[col0[e]], 1);
}

__global__ void k_dinv(const int* __restrict__ cnt, float* __restrict__ dinv) {
    int i = blockIdx.x * blockDim.x + threadIdx.x;
    if (i >= NN) return;
    int d = cnt[i];
    dinv[i] = (d > 0) ? rsqrtf((float)d) : 0.0f;
}

__global__ void k_norm(const int* __restrict__ row0, const int* __restrict__ col0,
                       const float* __restrict__ dinv, float* __restrict__ norm) {
    int e = blockIdx.x * blockDim.x + threadIdx.x;
    if (e >= NE) return;
    norm[e] = dinv[row0[e]] * dinv[col0[e]];
}

// --- 3-stage exclusive scan over cnt[NN] -> ptr[NN+1] ---
__global__ void k_scan1(const int* __restrict__ cnt, int* __restrict__ excl,
                        int* __restrict__ bsum) {
    __shared__ int sm[SCAN_CHUNK];
    int tid = threadIdx.x;
    int idx = blockIdx.x * SCAN_CHUNK + tid;
    int x = (idx < NN) ? cnt[idx] : 0;
    sm[tid] = x;
    __syncthreads();
    for (int off = 1; off < SCAN_CHUNK; off <<= 1) {
        int v = (tid >= off) ? sm[tid - off] : 0;
        __syncthreads();
        sm[tid] += v;
        __syncthreads();
    }
    if (idx < NN) excl[idx] = sm[tid] - x;
    if (tid == SCAN_CHUNK - 1) bsum[blockIdx.x] = sm[tid];
}

__global__ void k_scan2(int* __restrict__ bsum, int* __restrict__ offs) {
    __shared__ int sm[256];
    int tid = threadIdx.x;
    int x = (tid < NBLK_SCAN) ? bsum[tid] : 0;
    sm[tid] = x;
    __syncthreads();
    for (int off = 1; off < 256; off <<= 1) {
        int v = (tid >= off) ? sm[tid - off] : 0;
        __syncthreads();
        sm[tid] += v;
        __syncthreads();
    }
    if (tid < NBLK_SCAN) offs[tid] = sm[tid] - x;
}

__global__ void k_scan3(const int* __restrict__ excl, const int* __restrict__ offs,
                        int* __restrict__ ptr) {
    int idx = blockIdx.x * blockDim.x + threadIdx.x;
    if (idx < NN) ptr[idx] = excl[idx] + offs[idx / SCAN_CHUNK];
    if (idx == NN) ptr[NN] = 2 * NE;
}

__global__ void k_fill(const int* __restrict__ row0, const int* __restrict__ col0,
                       int* __restrict__ pos, int* __restrict__ adj) {
    int e = blockIdx.x * blockDim.x + threadIdx.x;
    if (e >= NE) return;
    int r = row0[e], c = col0[e];
    int j = atomicAdd(&pos[c], 1);
    adj[j] = e;            // dir0: dst=c, src=r
    int j2 = atomicAdd(&pos[r], 1);
    adj[j2] = e + NE;      // dir1: dst=r, src=c
}

__global__ void k_softmax(const float* __restrict__ Sin, float* __restrict__ softS) {
    int e = blockIdx.x * blockDim.x + threadIdx.x;
    if (e >= NE) return;
    float s0 = Sin[e], s1 = Sin[NE + e], s2 = Sin[2 * NE + e], s3 = Sin[3 * NE + e];
    float m = fmaxf(fmaxf(s0, s1), fmaxf(s2, s3));
    float e0 = expf(s0 - m), e1 = expf(s1 - m), e2 = expf(s2 - m), e3 = expf(s3 - m);
    float inv = 1.0f / (e0 + e1 + e2 + e3);
    softS[e] = e0 * inv;
    softS[NE + e] = e1 * inv;
    softS[2 * NE + e] = e2 * inv;
    softS[3 * NE + e] = e3 * inv;
}

// gather conv: one wave per node, accumulate over incident directed edges
__global__ __launch_bounds__(256) void k_conv_csr(
        const int* __restrict__ row0, const int* __restrict__ col0,
        const int* __restrict__ ptr, const int* __restrict__ adj,
        const float* __restrict__ norm, const float* __restrict__ softS,
        const float* __restrict__ ego, float* __restrict__ xnew) {
    int node = (blockIdx.x * blockDim.x + threadIdx.x) >> 6;
    int lane = threadIdx.x & 63;
    if (node >= NN) return;
    int beg = ptr[node], end = ptr[node + 1];
    int k = lane >> 4;
    float acc = 0.0f;
    for (int j = beg; j < end; ++j) {
        int id = adj[j];
        int e = (id < NE) ? id : id - NE;
        int src = (id < NE) ? row0[e] : col0[e];
        float w = norm[e] * softS[k * NE + e];
        acc = fmaf(w, ego[src * DIM + lane], acc);
    }
    xnew[node * DIM + lane] = acc;
}

// per-node T = tanh(l2norm(ego row per factor)) — constant within a layer
__global__ void k_tanh(const float* __restrict__ ego, float* __restrict__ T) {
    int node = (blockIdx.x * blockDim.x + threadIdx.x) >> 6;
    int lane = threadIdx.x & 63;
    if (node >= NN) return;
    float x = ego[node * DIM + lane];
    float ss = red16(x * x);
    float v = x / fmaxf(sqrtf(ss), 1e-12f);
    T[node * DIM + lane] = tanhf(v);
}

// S_out[k][e] = softS[k][e] + dot(l2n(xnew[row]), T[col])
__global__ void k_score(const int* __restrict__ row0, const int* __restrict__ col0,
                        const float* __restrict__ softS, const float* __restrict__ xnew,
                        const float* __restrict__ T, float* __restrict__ Sout) {
    int wid = (blockIdx.x * blockDim.x + threadIdx.x) >> 6;
    int lane = threadIdx.x & 63;
    if (wid >= NE) return;
    int r = row0[wid], c = col0[wid];
    float xu = xnew[r * DIM + lane];
    float tc = T[c * DIM + lane];
    float ssu = red16(xu * xu);
    float u = xu / fmaxf(sqrtf(ssu), 1e-12f);
    float p = red16(u * tc);
    if ((lane & 15) == 0) {
        int k = lane >> 4;
        Sout[k * NE + wid] = softS[k * NE + wid] + p;
    }
}

__global__ void k_accum(const float* __restrict__ xnew, float* __restrict__ allemb) {
    int i = blockIdx.x * blockDim.x + threadIdx.x;
    if (i >= NN * DIM) return;
    allemb[i] += xnew[i];
}

extern "C" void kernel_launch(void* const* d_in, const int* in_sizes, int n_in,
                              void* d_out, int out_size, void* d_ws, size_t ws_size,
                              hipStream_t stream) {
    const float* user = (const float*)d_in[0];
    const float* item = (const float*)d_in[1];
    const float* S_in = (const float*)d_in[2];
    const int* edge = (const int*)d_in[3];
    const int* row0 = edge;
    const int* col0 = edge + NE;

    float* out = (float*)d_out;
    float* allemb = out;              // NN*DIM floats
    float* Scur = out + NN * DIM;     // KF*NE floats (final S lives here)

    char* ws = (char*)d_ws;
    size_t off = 0;
    auto carve = [&](size_t bytes) { void* p = ws + off; off += (bytes + 255) & ~(size_t)255; return p; };
    int* cnt = (int*)carve(NN * sizeof(int));
    int* excl = (int*)carve(NN * sizeof(int));
    int* bsum = (int*)carve(256 * sizeof(int));
    int* offs = (int*)carve(256 * sizeof(int));
    int* ptr = (int*)carve((NN + 1) * sizeof(int));
    int* pos = (int*)carve((NN + 1) * sizeof(int));
    int* adj = (int*)carve((size_t)2 * NE * sizeof(int));
    float* dinv = (float*)carve(NN * sizeof(float));
    float* norm = (float*)carve(NE * sizeof(float));
    float* softS = (float*)carve((size_t)KF * NE * sizeof(float));
    float* egoA = (float*)carve((size_t)NN * DIM * sizeof(float));
    float* egoB = (float*)carve((size_t)NN * DIM * sizeof(float));
    float* T = (float*)carve((size_t)NN * DIM * sizeof(float));

    hipMemsetAsync(cnt, 0, NN * sizeof(int), stream);
    hipMemcpyAsync(Scur, S_in, (size_t)KF * NE * sizeof(float),
                   hipMemcpyDeviceToDevice, stream);

    k_init<<<(NN * DIM + 255) / 256, 256, 0, stream>>>(user, item, egoA, allemb);
    k_count<<<(NE + 255) / 256, 256, 0, stream>>>(row0, col0, cnt);
    k_dinv<<<(NN + 255) / 256, 256, 0, stream>>>(cnt, dinv);
    k_norm<<<(NE + 255) / 256, 256, 0, stream>>>(row0, col0, dinv, norm);

    k_scan1<<<NBLK_SCAN, SCAN_CHUNK, 0, stream>>>(cnt, excl, bsum);
    k_scan2<<<1, 256, 0, stream>>>(bsum, offs);
    k_scan3<<<(NN + 1 + 255) / 256, 256, 0, stream>>>(excl, offs, ptr);
    hipMemcpyAsync(pos, ptr, (NN + 1) * sizeof(int), hipMemcpyDeviceToDevice, stream);
    k_fill<<<(NE + 255) / 256, 256, 0, stream>>>(row0, col0, pos, adj);

    float* ego = egoA;
    float* xnew = egoB;
    for (int layer = 0; layer < 2; ++layer) {
        k_tanh<<<(NN * 64 + 255) / 256, 256, 0, stream>>>(ego, T);
        for (int it = 0; it < 2; ++it) {
            k_softmax<<<(NE + 255) / 256, 256, 0, stream>>>(Scur, softS);
            k_conv_csr<<<(NN * 64 + 255) / 256, 256, 0, stream>>>(
                row0, col0, ptr, adj, norm, softS, ego, xnew);
            k_score<<<(NE * 64 + 255) / 256, 256, 0, stream>>>(
                row0, col0, softS, xnew, T, Scur);
        }
        k_accum<<<(NN * DIM + 255) / 256, 256, 0, stream>>>(xnew, allemb);
        float* t = ego; ego = xnew; xnew = t;
    }
}

// Round 3
// 1022.030 us; speedup vs baseline: 1.5135x; 1.3011x over previous
//
#include <hip/hip_runtime.h>

#define NUM_USER 60000
#define NUM_ITEM 40000
#define NN 100000
#define NE 500000
#define DIM 64
#define KF 4
#define SCAN_CHUNK 512
#define NBLK_SCAN ((NN + 1 + SCAN_CHUNK - 1) / SCAN_CHUNK)

// sum within each 16-lane group of the wave
__device__ __forceinline__ float red16(float v) {
    v += __shfl_xor(v, 1);
    v += __shfl_xor(v, 2);
    v += __shfl_xor(v, 4);
    v += __shfl_xor(v, 8);
    return v;
}

__device__ __forceinline__ float4 softmax4(float4 s) {
    float m = fmaxf(fmaxf(s.x, s.y), fmaxf(s.z, s.w));
    float e0 = expf(s.x - m), e1 = expf(s.y - m), e2 = expf(s.z - m), e3 = expf(s.w - m);
    float inv = 1.0f / (e0 + e1 + e2 + e3);
    return make_float4(e0 * inv, e1 * inv, e2 * inv, e3 * inv);
}

__global__ void k_init(const float* __restrict__ user, const float* __restrict__ item,
                       float* __restrict__ ego, float* __restrict__ allemb) {
    int i = blockIdx.x * blockDim.x + threadIdx.x;
    if (i >= NN * DIM) return;
    float v = (i < NUM_USER * DIM) ? user[i] : item[i - NUM_USER * DIM];
    ego[i] = v;
    allemb[i] = v;
}

// S_in [4][E] -> Scur4 [E] float4
__global__ void k_sin(const float* __restrict__ Sin, float4* __restrict__ Scur4) {
    int e = blockIdx.x * blockDim.x + threadIdx.x;
    if (e >= NE) return;
    Scur4[e] = make_float4(Sin[e], Sin[NE + e], Sin[2 * NE + e], Sin[3 * NE + e]);
}

// Scur4 [E] float4 -> Sout [4][E]
__global__ void k_sout(const float4* __restrict__ Scur4, float* __restrict__ Sout) {
    int e = blockIdx.x * blockDim.x + threadIdx.x;
    if (e >= NE) return;
    float4 s = Scur4[e];
    Sout[e] = s.x;
    Sout[NE + e] = s.y;
    Sout[2 * NE + e] = s.z;
    Sout[3 * NE + e] = s.w;
}

__global__ void k_count(const int* __restrict__ row0, const int* __restrict__ col0,
                        int* __restrict__ cnt) {
    int e = blockIdx.x * blockDim.x + threadIdx.x;
    if (e >= NE) return;
    atomicAdd(&cnt[row0[e]], 1);
    atomicAdd(&cnt[col0[e]], 1);
}

__global__ void k_dinv(const int* __restrict__ cnt, float* __restrict__ dinv) {
    int i = blockIdx.x * blockDim.x + threadIdx.x;
    if (i >= NN) return;
    int d = cnt[i];
    dinv[i] = (d > 0) ? rsqrtf((float)d) : 0.0f;
}

__global__ void k_norm(const int* __restrict__ row0, const int* __restrict__ col0,
                       const float* __restrict__ dinv, float* __restrict__ norm) {
    int e = blockIdx.x * blockDim.x + threadIdx.x;
    if (e >= NE) return;
    norm[e] = dinv[row0[e]] * dinv[col0[e]];
}

// --- 3-stage exclusive scan over cnt[NN] -> ptr[NN+1] ---
__global__ void k_scan1(const int* __restrict__ cnt, int* __restrict__ ptr,
                        int* __restrict__ bsum) {
    __shared__ int sm[SCAN_CHUNK];
    int tid = threadIdx.x;
    int idx = blockIdx.x * SCAN_CHUNK + tid;
    int x = (idx < NN) ? cnt[idx] : 0;
    sm[tid] = x;
    __syncthreads();
    for (int off = 1; off < SCAN_CHUNK; off <<= 1) {
        int v = (tid >= off) ? sm[tid - off] : 0;
        __syncthreads();
        sm[tid] += v;
        __syncthreads();
    }
    if (idx <= NN) ptr[idx] = sm[tid] - x;
    if (tid == SCAN_CHUNK - 1) bsum[blockIdx.x] = sm[tid];
}

__global__ void k_scan2(int* __restrict__ bsum, int* __restrict__ offs) {
    __shared__ int sm[256];
    int tid = threadIdx.x;
    int x = (tid < NBLK_SCAN) ? bsum[tid] : 0;
    sm[tid] = x;
    __syncthreads();
    for (int off = 1; off < 256; off <<= 1) {
        int v = (tid >= off) ? sm[tid - off] : 0;
        __syncthreads();
        sm[tid] += v;
        __syncthreads();
    }
    if (tid < NBLK_SCAN) offs[tid] = sm[tid] - x;
}

__global__ void k_scan3(int* __restrict__ ptr, const int* __restrict__ offs) {
    int idx = blockIdx.x * blockDim.x + threadIdx.x;
    if (idx <= NN) ptr[idx] += offs[idx / SCAN_CHUNK];
}

// build per-slot source + per-edge slot positions
__global__ void k_fill(const int* __restrict__ row0, const int* __restrict__ col0,
                       int* __restrict__ pos, int* __restrict__ srcadj,
                       int* __restrict__ jpos0, int* __restrict__ jpos1) {
    int e = blockIdx.x * blockDim.x + threadIdx.x;
    if (e >= NE) return;
    int r = row0[e], c = col0[e];
    int j0 = atomicAdd(&pos[c], 1);   // slot with dst=c (item side), src=r
    srcadj[j0] = r;
    jpos0[e] = j0;
    int j1 = atomicAdd(&pos[r], 1);   // slot with dst=r (user side), src=c
    srcadj[j1] = c;
    jpos1[e] = j1;
}

// per-edge: w4 = norm * softmax(Scur), scattered to both adjacency slots
__global__ void k_wadj(const float4* __restrict__ Scur4, const float* __restrict__ norm,
                       const int* __restrict__ jpos0, const int* __restrict__ jpos1,
                       float4* __restrict__ wadj) {
    int e = blockIdx.x * blockDim.x + threadIdx.x;
    if (e >= NE) return;
    float4 p = softmax4(Scur4[e]);
    float n = norm[e];
    float4 w = make_float4(n * p.x, n * p.y, n * p.z, n * p.w);
    wadj[jpos0[e]] = w;
    wadj[jpos1[e]] = w;
}

// gather conv: one wave per node, fully sequential weight/index streams
__global__ __launch_bounds__(256) void k_conv(
        const int* __restrict__ ptr, const int* __restrict__ srcadj,
        const float4* __restrict__ wadj, const float* __restrict__ ego,
        float* __restrict__ xnew) {
    int node = (blockIdx.x * blockDim.x + threadIdx.x) >> 6;
    int lane = threadIdx.x & 63;
    if (node >= NN) return;
    int beg = ptr[node], end = ptr[node + 1];
    int k = lane >> 4;
    const float* wf = (const float*)wadj;
    float acc = 0.0f;
    for (int j = beg; j < end; ++j) {
        int src = srcadj[j];
        float w = wf[4 * j + k];
        acc = fmaf(w, ego[src * DIM + lane], acc);
    }
    xnew[node * DIM + lane] = acc;
}

// per-node T = tanh(l2norm per factor) — constant within a layer
__global__ void k_tanh(const float* __restrict__ ego, float* __restrict__ T) {
    int node = (blockIdx.x * blockDim.x + threadIdx.x) >> 6;
    int lane = threadIdx.x & 63;
    if (node >= NN) return;
    float x = ego[node * DIM + lane];
    float ss = red16(x * x);
    float v = x / fmaxf(sqrtf(ss), 1e-12f);
    T[node * DIM + lane] = tanhf(v);
}

// wave per user node: u = l2n(xnew[r]) once; dot against gathered T rows
__global__ __launch_bounds__(256) void k_score(
        const int* __restrict__ ptr, const int* __restrict__ srcadj,
        const float* __restrict__ xnew, const float* __restrict__ T,
        float* __restrict__ pscore) {
    int r = (blockIdx.x * blockDim.x + threadIdx.x) >> 6;
    int lane = threadIdx.x & 63;
    if (r >= NUM_USER) return;
    float xu = xnew[r * DIM + lane];
    float ssu = red16(xu * xu);
    float u = xu / fmaxf(sqrtf(ssu), 1e-12f);
    int beg = ptr[r], end = ptr[r + 1];
    for (int j = beg; j < end; ++j) {
        int c = srcadj[j];
        float p = red16(u * T[c * DIM + lane]);
        if ((lane & 15) == 0) pscore[4 * j + (lane >> 4)] = p;
    }
}

// S = softmax(S) + p  (in place, [E][4] layout)
__global__ void k_snew(float4* __restrict__ Scur4, const float4* __restrict__ pscore,
                       const int* __restrict__ jpos1) {
    int e = blockIdx.x * blockDim.x + threadIdx.x;
    if (e >= NE) return;
    float4 s = softmax4(Scur4[e]);
    float4 p = pscore[jpos1[e]];
    Scur4[e] = make_float4(s.x + p.x, s.y + p.y, s.z + p.z, s.w + p.w);
}

__global__ void k_accum(const float* __restrict__ xnew, float* __restrict__ allemb) {
    int i = blockIdx.x * blockDim.x + threadIdx.x;
    if (i >= NN * DIM) return;
    allemb[i] += xnew[i];
}

extern "C" void kernel_launch(void* const* d_in, const int* in_sizes, int n_in,
                              void* d_out, int out_size, void* d_ws, size_t ws_size,
                              hipStream_t stream) {
    const float* user = (const float*)d_in[0];
    const float* item = (const float*)d_in[1];
    const float* S_in = (const float*)d_in[2];
    const int* edge = (const int*)d_in[3];
    const int* row0 = edge;
    const int* col0 = edge + NE;

    float* out = (float*)d_out;
    float* allemb = out;              // NN*DIM floats
    float* Sfinal = out + NN * DIM;   // KF*NE floats

    char* ws = (char*)d_ws;
    size_t off = 0;
    auto carve = [&](size_t bytes) { void* p = ws + off; off += (bytes + 255) & ~(size_t)255; return p; };
    int* cnt = (int*)carve((NN + 1) * sizeof(int));
    int* ptr = (int*)carve((NN + 1) * sizeof(int));
    int* pos = (int*)carve((NN + 1) * sizeof(int));
    int* bsum = (int*)carve(256 * sizeof(int));
    int* offs = (int*)carve(256 * sizeof(int));
    int* srcadj = (int*)carve((size_t)2 * NE * sizeof(int));
    int* jpos0 = (int*)carve((size_t)NE * sizeof(int));
    int* jpos1 = (int*)carve((size_t)NE * sizeof(int));
    float* dinv = (float*)carve(NN * sizeof(float));
    float* norm = (float*)carve(NE * sizeof(float));
    float4* Scur4 = (float4*)carve((size_t)NE * sizeof(float4));
    float4* wadj = (float4*)carve((size_t)2 * NE * sizeof(float4));
    float4* pscore = wadj;            // alias: wadj dead after conv, pscore born in score
    float* egoA = (float*)carve((size_t)NN * DIM * sizeof(float));
    float* egoB = (float*)carve((size_t)NN * DIM * sizeof(float));
    float* T = (float*)carve((size_t)NN * DIM * sizeof(float));

    hipMemsetAsync(cnt, 0, (NN + 1) * sizeof(int), stream);

    k_init<<<(NN * DIM + 255) / 256, 256, 0, stream>>>(user, item, egoA, allemb);
    k_sin<<<(NE + 255) / 256, 256, 0, stream>>>(S_in, Scur4);
    k_count<<<(NE + 255) / 256, 256, 0, stream>>>(row0, col0, cnt);
    k_dinv<<<(NN + 255) / 256, 256, 0, stream>>>(cnt, dinv);
    k_norm<<<(NE + 255) / 256, 256, 0, stream>>>(row0, col0, dinv, norm);

    k_scan1<<<NBLK_SCAN, SCAN_CHUNK, 0, stream>>>(cnt, ptr, bsum);
    k_scan2<<<1, 256, 0, stream>>>(bsum, offs);
    k_scan3<<<(NN + 1 + 255) / 256, 256, 0, stream>>>(ptr, offs);
    hipMemcpyAsync(pos, ptr, (NN + 1) * sizeof(int), hipMemcpyDeviceToDevice, stream);
    k_fill<<<(NE + 255) / 256, 256, 0, stream>>>(row0, col0, pos, srcadj, jpos0, jpos1);

    float* ego = egoA;
    float* xnew = egoB;
    for (int layer = 0; layer < 2; ++layer) {
        k_tanh<<<(NN * 64 + 255) / 256, 256, 0, stream>>>(ego, T);
        for (int it = 0; it < 2; ++it) {
            k_wadj<<<(NE + 255) / 256, 256, 0, stream>>>(Scur4, norm, jpos0, jpos1, wadj);
            k_conv<<<(NN * 64 + 255) / 256, 256, 0, stream>>>(ptr, srcadj, wadj, ego, xnew);
            k_score<<<(NUM_USER * 64 + 255) / 256, 256, 0, stream>>>(ptr, srcadj, xnew, T, (float*)pscore);
            k_snew<<<(NE + 255) / 256, 256, 0, stream>>>(Scur4, pscore, jpos1);
        }
        k_accum<<<(NN * DIM + 255) / 256, 256, 0, stream>>>(xnew, allemb);
        float* t = ego; ego = xnew; xnew = t;
    }
    k_sout<<<(NE + 255) / 256, 256, 0, stream>>>(Scur4, Sfinal);
}

// Round 4
// 699.361 us; speedup vs baseline: 2.2119x; 1.4614x over previous
//
#include <hip/hip_runtime.h>

#define NUM_USER 60000
#define NUM_ITEM 40000
#define NN 100000
#define NE 500000
#define DIM 64
#define KF 4
#define SCAN_CHUNK 512
#define NBLK_SCAN ((NN + 1 + SCAN_CHUNK - 1) / SCAN_CHUNK)

// sum within each 16-lane group of the wave
__device__ __forceinline__ float red16(float v) {
    v += __shfl_xor(v, 1);
    v += __shfl_xor(v, 2);
    v += __shfl_xor(v, 4);
    v += __shfl_xor(v, 8);
    return v;
}

__device__ __forceinline__ float4 softmax4(float4 s) {
    float m = fmaxf(fmaxf(s.x, s.y), fmaxf(s.z, s.w));
    float e0 = expf(s.x - m), e1 = expf(s.y - m), e2 = expf(s.z - m), e3 = expf(s.w - m);
    float inv = 1.0f / (e0 + e1 + e2 + e3);
    return make_float4(e0 * inv, e1 * inv, e2 * inv, e3 * inv);
}

// wave per node: ego = concat(user,item); allemb = ego; T = tanh(l2n16(ego))
__global__ void k_init_tanh(const float* __restrict__ user, const float* __restrict__ item,
                            float* __restrict__ ego, float* __restrict__ allemb,
                            float* __restrict__ T) {
    int node = (blockIdx.x * blockDim.x + threadIdx.x) >> 6;
    int lane = threadIdx.x & 63;
    if (node >= NN) return;
    int i = node * DIM + lane;
    float v = (node < NUM_USER) ? user[i] : item[i - NUM_USER * DIM];
    ego[i] = v;
    allemb[i] = v;
    float ss = red16(v * v);
    T[i] = tanhf(v / fmaxf(sqrtf(ss), 1e-12f));
}

// S_in [4][E] -> Scur4 [E] float4
__global__ void k_sin(const float* __restrict__ Sin, float4* __restrict__ Scur4) {
    int e = blockIdx.x * blockDim.x + threadIdx.x;
    if (e >= NE) return;
    Scur4[e] = make_float4(Sin[e], Sin[NE + e], Sin[2 * NE + e], Sin[3 * NE + e]);
}

// Scur4 [E] float4 -> Sout [4][E]
__global__ void k_sout(const float4* __restrict__ Scur4, float* __restrict__ Sout) {
    int e = blockIdx.x * blockDim.x + threadIdx.x;
    if (e >= NE) return;
    float4 s = Scur4[e];
    Sout[e] = s.x;
    Sout[NE + e] = s.y;
    Sout[2 * NE + e] = s.z;
    Sout[3 * NE + e] = s.w;
}

__global__ void k_count(const int* __restrict__ row0, const int* __restrict__ col0,
                        int* __restrict__ cnt) {
    int e = blockIdx.x * blockDim.x + threadIdx.x;
    if (e >= NE) return;
    atomicAdd(&cnt[row0[e]], 1);
    atomicAdd(&cnt[col0[e]], 1);
}

__global__ void k_dinv(const int* __restrict__ cnt, float* __restrict__ dinv) {
    int i = blockIdx.x * blockDim.x + threadIdx.x;
    if (i >= NN) return;
    int d = cnt[i];
    dinv[i] = (d > 0) ? rsqrtf((float)d) : 0.0f;
}

__global__ void k_norm(const int* __restrict__ row0, const int* __restrict__ col0,
                       const float* __restrict__ dinv, float* __restrict__ norm) {
    int e = blockIdx.x * blockDim.x + threadIdx.x;
    if (e >= NE) return;
    norm[e] = dinv[row0[e]] * dinv[col0[e]];
}

// --- 3-stage exclusive scan over cnt[NN] -> ptr[NN+1] ---
__global__ void k_scan1(const int* __restrict__ cnt, int* __restrict__ ptr,
                        int* __restrict__ bsum) {
    __shared__ int sm[SCAN_CHUNK];
    int tid = threadIdx.x;
    int idx = blockIdx.x * SCAN_CHUNK + tid;
    int x = (idx < NN) ? cnt[idx] : 0;
    sm[tid] = x;
    __syncthreads();
    for (int off = 1; off < SCAN_CHUNK; off <<= 1) {
        int v = (tid >= off) ? sm[tid - off] : 0;
        __syncthreads();
        sm[tid] += v;
        __syncthreads();
    }
    if (idx <= NN) ptr[idx] = sm[tid] - x;
    if (tid == SCAN_CHUNK - 1) bsum[blockIdx.x] = sm[tid];
}

__global__ void k_scan2(int* __restrict__ bsum, int* __restrict__ offs) {
    __shared__ int sm[256];
    int tid = threadIdx.x;
    int x = (tid < NBLK_SCAN) ? bsum[tid] : 0;
    sm[tid] = x;
    __syncthreads();
    for (int off = 1; off < 256; off <<= 1) {
        int v = (tid >= off) ? sm[tid - off] : 0;
        __syncthreads();
        sm[tid] += v;
        __syncthreads();
    }
    if (tid < NBLK_SCAN) offs[tid] = sm[tid] - x;
}

__global__ void k_scan3(int* __restrict__ ptr, const int* __restrict__ offs) {
    int idx = blockIdx.x * blockDim.x + threadIdx.x;
    if (idx <= NN) ptr[idx] += offs[idx / SCAN_CHUNK];
}

// build per-slot source + per-edge slot positions
__global__ void k_fill(const int* __restrict__ row0, const int* __restrict__ col0,
                       int* __restrict__ pos, int* __restrict__ srcadj,
                       int* __restrict__ jpos0, int* __restrict__ jpos1) {
    int e = blockIdx.x * blockDim.x + threadIdx.x;
    if (e >= NE) return;
    int r = row0[e], c = col0[e];
    int j0 = atomicAdd(&pos[c], 1);   // slot with dst=c (item side), src=r
    srcadj[j0] = r;
    jpos0[e] = j0;
    int j1 = atomicAdd(&pos[r], 1);   // slot with dst=r (user side), src=c
    srcadj[j1] = c;
    jpos1[e] = j1;
}

// per-edge: w4 = norm * softmax(Scur), scattered to both adjacency slots
__global__ void k_wadj(const float4* __restrict__ Scur4, const float* __restrict__ norm,
                       const int* __restrict__ jpos0, const int* __restrict__ jpos1,
                       float4* __restrict__ wadj) {
    int e = blockIdx.x * blockDim.x + threadIdx.x;
    if (e >= NE) return;
    float4 p = softmax4(Scur4[e]);
    float n = norm[e];
    float4 w = make_float4(n * p.x, n * p.y, n * p.z, n * p.w);
    wadj[jpos0[e]] = w;
    wadj[jpos1[e]] = w;
}

// fused gather conv + routing score. wave per node.
// wp is BOTH the weight stream (read, loop 1) and the pscore output (write,
// loop 2, user nodes only). Alias is safe: every loop-2 store depends on u,
// which depends on every loop-1 weight load of this same wave's slots, and
// slot ranges of distinct nodes are disjoint.
__global__ __launch_bounds__(256) void k_conv_score(
        const int* __restrict__ ptr, const int* __restrict__ srcadj,
        float* wp, const float* __restrict__ ego,
        const float* __restrict__ T, float* __restrict__ xnew) {
    int node = (blockIdx.x * blockDim.x + threadIdx.x) >> 6;
    int lane = threadIdx.x & 63;
    if (node >= NN) return;
    int beg = ptr[node], end = ptr[node + 1];
    int k = lane >> 4;

    // ---- conv: unroll x4, independent chains for MLP ----
    float a0 = 0.0f, a1 = 0.0f, a2 = 0.0f, a3 = 0.0f;
    int j = beg;
    for (; j + 4 <= end; j += 4) {
        int s0 = srcadj[j + 0], s1 = srcadj[j + 1];
        int s2 = srcadj[j + 2], s3 = srcadj[j + 3];
        float w0 = wp[4 * (j + 0) + k], w1 = wp[4 * (j + 1) + k];
        float w2 = wp[4 * (j + 2) + k], w3 = wp[4 * (j + 3) + k];
        a0 = fmaf(w0, ego[s0 * DIM + lane], a0);
        a1 = fmaf(w1, ego[s1 * DIM + lane], a1);
        a2 = fmaf(w2, ego[s2 * DIM + lane], a2);
        a3 = fmaf(w3, ego[s3 * DIM + lane], a3);
    }
    for (; j < end; ++j)
        a0 = fmaf(wp[4 * j + k], ego[srcadj[j] * DIM + lane], a0);
    float acc = (a0 + a1) + (a2 + a3);
    xnew[node * DIM + lane] = acc;

    // ---- score (user nodes only): u = l2n16(acc); dot vs T rows ----
    if (node >= NUM_USER) return;
    float ssu = red16(acc * acc);
    float u = acc / fmaxf(sqrtf(ssu), 1e-12f);
    j = beg;
    for (; j + 2 <= end; j += 2) {
        int s0 = srcadj[j], s1 = srcadj[j + 1];
        float t0 = T[s0 * DIM + lane];
        float t1 = T[s1 * DIM + lane];
        float p0 = red16(u * t0);
        float p1 = red16(u * t1);
        if ((lane & 15) == 0) {
            wp[4 * j + k] = p0;
            wp[4 * (j + 1) + k] = p1;
        }
    }
    for (; j < end; ++j) {
        float p = red16(u * T[srcadj[j] * DIM + lane]);
        if ((lane & 15) == 0) wp[4 * j + k] = p;
    }
}

// S = softmax(S) + p  (in place, [E][4] layout)
__global__ void k_snew(float4* __restrict__ Scur4, const float4* __restrict__ pscore,
                       const int* __restrict__ jpos1) {
    int e = blockIdx.x * blockDim.x + threadIdx.x;
    if (e >= NE) return;
    float4 s = softmax4(Scur4[e]);
    float4 p = pscore[jpos1[e]];
    Scur4[e] = make_float4(s.x + p.x, s.y + p.y, s.z + p.z, s.w + p.w);
}

// wave per node: allemb += xnew; optionally T = tanh(l2n16(xnew)) for next layer
__global__ void k_accum_tanh(const float* __restrict__ xnew, float* __restrict__ allemb,
                             float* __restrict__ T, int do_tanh) {
    int node = (blockIdx.x * blockDim.x + threadIdx.x) >> 6;
    int lane = threadIdx.x & 63;
    if (node >= NN) return;
    int i = node * DIM + lane;
    float x = xnew[i];
    allemb[i] += x;
    if (do_tanh) {
        float ss = red16(x * x);
        T[i] = tanhf(x / fmaxf(sqrtf(ss), 1e-12f));
    }
}

extern "C" void kernel_launch(void* const* d_in, const int* in_sizes, int n_in,
                              void* d_out, int out_size, void* d_ws, size_t ws_size,
                              hipStream_t stream) {
    const float* user = (const float*)d_in[0];
    const float* item = (const float*)d_in[1];
    const float* S_in = (const float*)d_in[2];
    const int* edge = (const int*)d_in[3];
    const int* row0 = edge;
    const int* col0 = edge + NE;

    float* out = (float*)d_out;
    float* allemb = out;              // NN*DIM floats
    float* Sfinal = out + NN * DIM;   // KF*NE floats

    char* ws = (char*)d_ws;
    size_t off = 0;
    auto carve = [&](size_t bytes) { void* p = ws + off; off += (bytes + 255) & ~(size_t)255; return p; };
    int* cnt = (int*)carve((NN + 1) * sizeof(int));
    int* ptr = (int*)carve((NN + 1) * sizeof(int));
    int* pos = (int*)carve((NN + 1) * sizeof(int));
    int* bsum = (int*)carve(256 * sizeof(int));
    int* offs = (int*)carve(256 * sizeof(int));
    int* srcadj = (int*)carve((size_t)2 * NE * sizeof(int));
    int* jpos0 = (int*)carve((size_t)NE * sizeof(int));
    int* jpos1 = (int*)carve((size_t)NE * sizeof(int));
    float* dinv = (float*)carve(NN * sizeof(float));
    float* norm = (float*)carve(NE * sizeof(float));
    float4* Scur4 = (float4*)carve((size_t)NE * sizeof(float4));
    float4* wadj = (float4*)carve((size_t)2 * NE * sizeof(float4));  // also pscore
    float* egoA = (float*)carve((size_t)NN * DIM * sizeof(float));
    float* egoB = (float*)carve((size_t)NN * DIM * sizeof(float));
    float* T = (float*)carve((size_t)NN * DIM * sizeof(float));

    hipMemsetAsync(cnt, 0, (NN + 1) * sizeof(int), stream);

    k_init_tanh<<<(NN * 64 + 255) / 256, 256, 0, stream>>>(user, item, egoA, allemb, T);
    k_sin<<<(NE + 255) / 256, 256, 0, stream>>>(S_in, Scur4);
    k_count<<<(NE + 255) / 256, 256, 0, stream>>>(row0, col0, cnt);
    k_dinv<<<(NN + 255) / 256, 256, 0, stream>>>(cnt, dinv);
    k_norm<<<(NE + 255) / 256, 256, 0, stream>>>(row0, col0, dinv, norm);

    k_scan1<<<NBLK_SCAN, SCAN_CHUNK, 0, stream>>>(cnt, ptr, bsum);
    k_scan2<<<1, 256, 0, stream>>>(bsum, offs);
    k_scan3<<<(NN + 1 + 255) / 256, 256, 0, stream>>>(ptr, offs);
    hipMemcpyAsync(pos, ptr, (NN + 1) * sizeof(int), hipMemcpyDeviceToDevice, stream);
    k_fill<<<(NE + 255) / 256, 256, 0, stream>>>(row0, col0, pos, srcadj, jpos0, jpos1);

    float* ego = egoA;
    float* xnew = egoB;
    for (int layer = 0; layer < 2; ++layer) {
        for (int it = 0; it < 2; ++it) {
            k_wadj<<<(NE + 255) / 256, 256, 0, stream>>>(Scur4, norm, jpos0, jpos1, wadj);
            k_conv_score<<<(NN * 64 + 255) / 256, 256, 0, stream>>>(
                ptr, srcadj, (float*)wadj, ego, T, xnew);
            k_snew<<<(NE + 255) / 256, 256, 0, stream>>>(Scur4, wadj, jpos1);
        }
        k_accum_tanh<<<(NN * 64 + 255) / 256, 256, 0, stream>>>(
            xnew, allemb, T, layer == 0 ? 1 : 0);
        float* t = ego; ego = xnew; xnew = t;
    }
    k_sout<<<(NE + 255) / 256, 256, 0, stream>>>(Scur4, Sfinal);
}